// Round 1
// 1006.485 us; speedup vs baseline: 1.0338x; 1.0338x over previous
//
#include <hip/hip_runtime.h>
#include <math.h>

// TransformerLayer fused implementation for MI355X (gfx950).
// Reference quirks kept faithful:
//  - v / attended_values are DEAD code in the reference -> Wv never touched.
//  - scores scaled by 1/sqrt(D)=1/sqrt(2048), not 1/sqrt(head_dim).
//  - x2 = LN1(x) + x  (residual added to LN output).
// Outputs (concat in d_out): out [4,1024,2048] fp32, attn_probs [4,32,1024,1024] fp32.
//
// Workspace layout (needs ~151 MB):
//  4x WT bf16 (2048x2048), h/h2/q/k/a1 bf16 (4096x2048), x2 fp32 (4096x2048).
//
// R1 change: gemm_bf16 rewritten to the m97 structure (global_load_lds width=16,
// BK=64, 2-barrier loop) -- documented 517->874 TF step on this exact tile shape.

typedef unsigned short u16;
typedef u16    u16x8  __attribute__((ext_vector_type(8)));
typedef __bf16 bf16x8 __attribute__((ext_vector_type(8)));
typedef float  f32x4  __attribute__((ext_vector_type(4)));

#define MFMA16(a, b, c) __builtin_amdgcn_mfma_f32_16x16x32_bf16((a), (b), (c), 0, 0, 0)

__device__ __forceinline__ u16 f2bf(float f) {
  unsigned u = __builtin_bit_cast(unsigned, f);
  u += 0x7fffu + ((u >> 16) & 1u);   // RNE
  return (u16)(u >> 16);
}

// global -> LDS direct copy, 16 B per lane. LDS dest must be wave-uniform;
// HW writes ldsbase + lane*16.
__device__ __forceinline__ void gload_lds16(const u16* g, u16* l) {
  __builtin_amdgcn_global_load_lds(
      (const __attribute__((address_space(1))) unsigned int*)g,
      (__attribute__((address_space(3))) unsigned int*)l, 16, 0, 0);
}

// ---------------------------------------------------------------------------
// Weight transpose + fp32->bf16 cast:  W[K][N] -> WT[N][K]   (K=N=2048)
// ---------------------------------------------------------------------------
__global__ __launch_bounds__(256) void transpose_cast(const float* __restrict__ W,
                                                      u16* __restrict__ WT) {
  __shared__ u16 tile[64][65];  // 65: odd-ish stride breaks bank alignment
  const int n0 = blockIdx.x * 64, k0 = blockIdx.y * 64;
  const int c = threadIdx.x & 63, rb = threadIdx.x >> 6;
#pragma unroll
  for (int i = 0; i < 16; i++) {
    int r = rb + i * 4;
    tile[r][c] = f2bf(W[(size_t)(k0 + r) * 2048 + n0 + c]);
  }
  __syncthreads();
#pragma unroll
  for (int i = 0; i < 16; i++) {
    int r = rb + i * 4;
    WT[(size_t)(n0 + r) * 2048 + k0 + c] = tile[c][r];
  }
}

// ---------------------------------------------------------------------------
// Fused: h = LN1(x); x2 = h + x; h2 = LN2(x2).  One block per row (D=2048).
// ---------------------------------------------------------------------------
__device__ __forceinline__ float block_sum(float s, float* sbuf, int tid) {
#pragma unroll
  for (int off = 32; off; off >>= 1) s += __shfl_down(s, off, 64);
  __syncthreads();                       // protect sbuf reuse across calls
  if ((tid & 63) == 0) sbuf[tid >> 6] = s;
  __syncthreads();
  return sbuf[0] + sbuf[1] + sbuf[2] + sbuf[3];
}

__global__ __launch_bounds__(256) void ln_fused(
    const float* __restrict__ x,
    const float* __restrict__ s1, const float* __restrict__ b1,
    const float* __restrict__ s2, const float* __restrict__ b2,
    u16* __restrict__ h_bf, float* __restrict__ x2o, u16* __restrict__ h2_bf) {
  __shared__ float sbuf[4];
  const int row = blockIdx.x, tid = threadIdx.x;
  const size_t rbase = (size_t)row * 2048;
  const int c = tid * 8;

  float v[8];
  *(float4*)&v[0] = *(const float4*)(x + rbase + c);
  *(float4*)&v[4] = *(const float4*)(x + rbase + c + 4);

  float s = 0.f;
#pragma unroll
  for (int i = 0; i < 8; i++) s += v[i];
  const float m1 = block_sum(s, sbuf, tid) * (1.f / 2048.f);
  float ss = 0.f;
#pragma unroll
  for (int i = 0; i < 8; i++) { float d = v[i] - m1; ss += d * d; }
  const float r1 = rsqrtf(block_sum(ss, sbuf, tid) * (1.f / 2048.f) + 1e-5f);

  float w[8], bb[8];
  *(float4*)&w[0] = *(const float4*)(s1 + c);
  *(float4*)&w[4] = *(const float4*)(s1 + c + 4);
  *(float4*)&bb[0] = *(const float4*)(b1 + c);
  *(float4*)&bb[4] = *(const float4*)(b1 + c + 4);

  float xx[8];
  u16x8 hv;
#pragma unroll
  for (int i = 0; i < 8; i++) {
    float hh = (v[i] - m1) * r1 * w[i] + bb[i];
    xx[i] = hh + v[i];
    hv[i] = f2bf(hh);
  }
  *(u16x8*)(h_bf + rbase + c) = hv;
  *(float4*)(x2o + rbase + c) = *(float4*)&xx[0];
  *(float4*)(x2o + rbase + c + 4) = *(float4*)&xx[4];

  // LN2 on xx
  s = 0.f;
#pragma unroll
  for (int i = 0; i < 8; i++) s += xx[i];
  const float m2 = block_sum(s, sbuf, tid) * (1.f / 2048.f);
  ss = 0.f;
#pragma unroll
  for (int i = 0; i < 8; i++) { float d = xx[i] - m2; ss += d * d; }
  const float r2 = rsqrtf(block_sum(ss, sbuf, tid) * (1.f / 2048.f) + 1e-5f);

  *(float4*)&w[0] = *(const float4*)(s2 + c);
  *(float4*)&w[4] = *(const float4*)(s2 + c + 4);
  *(float4*)&bb[0] = *(const float4*)(b2 + c);
  *(float4*)&bb[4] = *(const float4*)(b2 + c + 4);
#pragma unroll
  for (int i = 0; i < 8; i++) hv[i] = f2bf((xx[i] - m2) * r2 * w[i] + bb[i]);
  *(u16x8*)(h2_bf + rbase + c) = hv;
}

// ---------------------------------------------------------------------------
// bf16 MFMA GEMM (m97 structure): C[M=4096][N=2048] = A[4096][2048] @ BT^T
// BT is the pre-transposed weight (BT[n][k] = W[k][n]), so both operands are
// k-contiguous. 128x128 block tile, BK=64, global_load_lds dwordx4 staging,
// 4 waves x (4x4) 16x16x32 MFMA tiles, 2-barrier K-loop.
//
// Staging geometry (per matrix, per K-step): 128 rows x 64 cols bf16 = 16 KB,
// 4 issues of 256 lanes x 16 B. Wave w, issue i covers rows [i*32+w*8, +8);
// lane l within the wave supplies row (l>>3), u16 col (l&7)*8. The LDS base
// (i*32+w*8)*64 is wave-uniform; HW scatters lane l at base + l*16 B, which
// matches the linear As[row][64] layout exactly.
// ---------------------------------------------------------------------------
template <int BIAS, int RELU, int RESID, int OUTBF>
__global__ __launch_bounds__(256) void gemm_bf16(
    const u16* __restrict__ A, const u16* __restrict__ BT,
    const float* __restrict__ bias, const float* __restrict__ resid,
    void* __restrict__ Cout) {
  constexpr int K = 2048, N = 2048, BK = 64;
  __shared__ u16 As[128 * BK];   // 16 KB
  __shared__ u16 Bs[128 * BK];   // 16 KB
  const int tid = threadIdx.x;
  const int row0 = blockIdx.y * 128, col0 = blockIdx.x * 128;
  const int wid = tid >> 6, lane = tid & 63, lr = lane & 15, quad = lane >> 4;
  const int wr0 = (wid >> 1) * 64, wc0 = (wid & 1) * 64;
  const int srow = lane >> 3;           // 0..7 row within 8-row group
  const int scol = (lane & 7) * 8;      // u16 col within BK

  f32x4 acc[4][4];
#pragma unroll
  for (int i = 0; i < 4; i++)
#pragma unroll
    for (int j = 0; j < 4; j++) acc[i][j] = (f32x4){0.f, 0.f, 0.f, 0.f};

  const u16* gA = A + (size_t)(row0 + srow) * K + scol;
  const u16* gB = BT + (size_t)(col0 + srow) * K + scol;

  for (int k0 = 0; k0 < K; k0 += BK) {
    if (k0) __syncthreads();   // previous compute done before LDS overwrite
#pragma unroll
    for (int i = 0; i < 4; i++) {
      const int rg = i * 32 + wid * 8;              // wave-uniform row group
      gload_lds16(gA + (size_t)rg * K + k0, &As[rg * BK]);
      gload_lds16(gB + (size_t)rg * K + k0, &Bs[rg * BK]);
    }
    __syncthreads();           // compiler drains vmcnt(0) before s_barrier

#pragma unroll
    for (int kk = 0; kk < 2; kk++) {
      bf16x8 af[4], bfr[4];
#pragma unroll
      for (int i = 0; i < 4; i++)
        af[i] = *(const bf16x8*)&As[(wr0 + i * 16 + lr) * BK + kk * 32 + quad * 8];
#pragma unroll
      for (int j = 0; j < 4; j++)
        bfr[j] = *(const bf16x8*)&Bs[(wc0 + j * 16 + lr) * BK + kk * 32 + quad * 8];
#pragma unroll
      for (int i = 0; i < 4; i++)
#pragma unroll
        for (int j = 0; j < 4; j++) acc[i][j] = MFMA16(af[i], bfr[j], acc[i][j]);
    }
  }

  // epilogue: C row = quad*4 + reg, col = lane&15 (verified gfx950 C/D layout)
#pragma unroll
  for (int i = 0; i < 4; i++) {
#pragma unroll
    for (int r = 0; r < 4; r++) {
      const int row = row0 + wr0 + i * 16 + quad * 4 + r;
#pragma unroll
      for (int j = 0; j < 4; j++) {
        const int col = col0 + wc0 + j * 16 + lr;
        float v = acc[i][j][r];
        if (BIAS) v += bias[col];
        if (RELU) v = fmaxf(v, 0.f);
        if (RESID) v += resid[(size_t)row * N + col];
        if (OUTBF)
          ((u16*)Cout)[(size_t)row * N + col] = f2bf(v);
        else
          ((float*)Cout)[(size_t)row * N + col] = v;
      }
    }
  }
}

// ---------------------------------------------------------------------------
// Attention scores + softmax, fused. One block = (b, h, 16 q-rows).
// scores[16][1024] in LDS (64 KB), probs written exactly once to d_out.
// q/k layout: [B*S][D] with col = h*64 + d  (i.e. the raw GEMM output).
// ---------------------------------------------------------------------------
__global__ __launch_bounds__(256) void attn_kernel(const u16* __restrict__ qm,
                                                   const u16* __restrict__ km,
                                                   float* __restrict__ probs) {
  __shared__ float sc[16 * 1024];
  const int tid = threadIdx.x, wid = tid >> 6, lane = tid & 63;
  const int lr = lane & 15, quad = lane >> 4;
  const int q0 = blockIdx.x * 16, h = blockIdx.y, b = blockIdx.z;

  const size_t qbase = (size_t)(b * 1024 + q0 + lr) * 2048 + h * 64 + quad * 8;
  const bf16x8 a0 = *(const bf16x8*)(qm + qbase);
  const bf16x8 a1 = *(const bf16x8*)(qm + qbase + 32);
  const float scale = 0.022097086912079608f;  // 1/sqrt(2048)

  for (int t = 0; t < 16; t++) {
    const int c0 = wid * 256 + t * 16;
    const size_t kbase = (size_t)(b * 1024 + c0 + lr) * 2048 + h * 64 + quad * 8;
    const bf16x8 b0 = *(const bf16x8*)(km + kbase);
    const bf16x8 b1 = *(const bf16x8*)(km + kbase + 32);
    f32x4 acc = (f32x4){0.f, 0.f, 0.f, 0.f};
    acc = MFMA16(a0, b0, acc);
    acc = MFMA16(a1, b1, acc);
#pragma unroll
    for (int r = 0; r < 4; r++) sc[(quad * 4 + r) * 1024 + c0 + lr] = acc[r] * scale;
  }
  __syncthreads();

#pragma unroll
  for (int rr = 0; rr < 4; rr++) {
    const int row = wid * 4 + rr;
    float vals[16];
    float mx = -1e30f;
#pragma unroll
    for (int i = 0; i < 16; i++) {
      vals[i] = sc[row * 1024 + lane + 64 * i];
      mx = fmaxf(mx, vals[i]);
    }
#pragma unroll
    for (int off = 32; off; off >>= 1) mx = fmaxf(mx, __shfl_xor(mx, off, 64));
    float sum = 0.f;
#pragma unroll
    for (int i = 0; i < 16; i++) {
      vals[i] = __expf(vals[i] - mx);
      sum += vals[i];
    }
#pragma unroll
    for (int off = 32; off; off >>= 1) sum += __shfl_xor(sum, off, 64);
    const float inv = 1.f / sum;
    float* pr = probs + (size_t)((b * 32 + h) * 1024 + q0 + row) * 1024;
#pragma unroll
    for (int i = 0; i < 16; i++) pr[lane + 64 * i] = vals[i] * inv;
  }
}

// ---------------------------------------------------------------------------
extern "C" void kernel_launch(void* const* d_in, const int* in_sizes, int n_in,
                              void* d_out, int out_size, void* d_ws, size_t ws_size,
                              hipStream_t stream) {
  const float* x = (const float*)d_in[0];
  const float* Wq = (const float*)d_in[1];
  const float* Wk = (const float*)d_in[2];
  // d_in[3] = Wv: dead in the reference (attended values are discarded)
  const float* ln1s = (const float*)d_in[4];
  const float* ln1b = (const float*)d_in[5];
  const float* ln2s = (const float*)d_in[6];
  const float* ln2b = (const float*)d_in[7];
  const float* f1w = (const float*)d_in[8];
  const float* f1b = (const float*)d_in[9];
  const float* f2w = (const float*)d_in[10];
  const float* f2b = (const float*)d_in[11];

  char* p = (char*)d_ws;
  const size_t WSZ = (size_t)2048 * 2048 * 2;   // 8 MB bf16 weight
  const size_t ASZ = (size_t)4096 * 2048 * 2;   // 16 MB bf16 activation
  u16* WqT = (u16*)p; p += WSZ;
  u16* WkT = (u16*)p; p += WSZ;
  u16* F1T = (u16*)p; p += WSZ;
  u16* F2T = (u16*)p; p += WSZ;
  u16* h_bf = (u16*)p; p += ASZ;
  u16* h2_bf = (u16*)p; p += ASZ;
  u16* q_bf = (u16*)p; p += ASZ;
  u16* k_bf = (u16*)p; p += ASZ;
  u16* a1_bf = (u16*)p; p += ASZ;
  float* x2 = (float*)p; p += (size_t)4096 * 2048 * 4;

  float* out = (float*)d_out;
  float* probs = out + (size_t)4096 * 2048;

  const dim3 tg(32, 32);
  transpose_cast<<<tg, 256, 0, stream>>>(Wq, WqT);
  transpose_cast<<<tg, 256, 0, stream>>>(Wk, WkT);
  transpose_cast<<<tg, 256, 0, stream>>>(f1w, F1T);
  transpose_cast<<<tg, 256, 0, stream>>>(f2w, F2T);

  ln_fused<<<4096, 256, 0, stream>>>(x, ln1s, ln1b, ln2s, ln2b, h_bf, x2, h2_bf);

  const dim3 gg(16, 32);
  gemm_bf16<0, 0, 0, 1><<<gg, 256, 0, stream>>>(h_bf, WqT, nullptr, nullptr, q_bf);
  gemm_bf16<0, 0, 0, 1><<<gg, 256, 0, stream>>>(h_bf, WkT, nullptr, nullptr, k_bf);

  attn_kernel<<<dim3(64, 32, 4), 256, 0, stream>>>(q_bf, k_bf, probs);

  gemm_bf16<1, 1, 0, 1><<<gg, 256, 0, stream>>>(h2_bf, F1T, f1b, nullptr, a1_bf);
  gemm_bf16<1, 0, 1, 0><<<gg, 256, 0, stream>>>(a1_bf, F2T, f2b, x2, out);
}

// Round 2
// 985.455 us; speedup vs baseline: 1.0558x; 1.0213x over previous
//
#include <hip/hip_runtime.h>
#include <math.h>

// TransformerLayer fused implementation for MI355X (gfx950).
// Reference quirks kept faithful:
//  - v / attended_values are DEAD code in the reference -> Wv never touched.
//  - scores scaled by 1/sqrt(D)=1/sqrt(2048), not 1/sqrt(head_dim).
//  - x2 = LN1(x) + x  (residual added to LN output).
// Outputs (concat in d_out): out [4,1024,2048] fp32, attn_probs [4,32,1024,1024] fp32.
//
// R2 changes (bundle, no GEMM sync-structure edits):
//  - Q+K GEMM merged into one N=4096 launch over [WqT;WkT] (contiguous in ws).
//  - 4 transpose_cast launches merged into one (blockIdx.z).
//  - attn softmax phase vectorized to float4 (LDS b128 reads, 1KB/instr stores).
//  - ln_fused: one wave per row, pure shfl reductions (no barriers, no LDS).

typedef unsigned short u16;
typedef u16    u16x4  __attribute__((ext_vector_type(4)));
typedef u16    u16x8  __attribute__((ext_vector_type(8)));
typedef __bf16 bf16x8 __attribute__((ext_vector_type(8)));
typedef float  f32x4  __attribute__((ext_vector_type(4)));

#define MFMA16(a, b, c) __builtin_amdgcn_mfma_f32_16x16x32_bf16((a), (b), (c), 0, 0, 0)

__device__ __forceinline__ u16 f2bf(float f) {
  unsigned u = __builtin_bit_cast(unsigned, f);
  u += 0x7fffu + ((u >> 16) & 1u);   // RNE
  return (u16)(u >> 16);
}

// global -> LDS direct copy, 16 B per lane. LDS dest must be wave-uniform;
// HW writes ldsbase + lane*16.
__device__ __forceinline__ void gload_lds16(const u16* g, u16* l) {
  __builtin_amdgcn_global_load_lds(
      (const __attribute__((address_space(1))) unsigned int*)g,
      (__attribute__((address_space(3))) unsigned int*)l, 16, 0, 0);
}

// ---------------------------------------------------------------------------
// Weight transpose + fp32->bf16 cast, all 4 weights in one launch.
// W[K][N] -> WT[N][K] (K=N=2048); blockIdx.z selects the matrix.
// ---------------------------------------------------------------------------
__global__ __launch_bounds__(256) void transpose_cast4(
    const float* __restrict__ W0, const float* __restrict__ W1,
    const float* __restrict__ W2, const float* __restrict__ W3,
    u16* __restrict__ dst) {
  __shared__ u16 tile[64][65];
  const int z = blockIdx.z;
  const float* W = (z == 0) ? W0 : (z == 1) ? W1 : (z == 2) ? W2 : W3;
  u16* WT = dst + (size_t)z * 2048 * 2048;
  const int n0 = blockIdx.x * 64, k0 = blockIdx.y * 64;
  const int c = threadIdx.x & 63, rb = threadIdx.x >> 6;
#pragma unroll
  for (int i = 0; i < 16; i++) {
    int r = rb + i * 4;
    tile[r][c] = f2bf(W[(size_t)(k0 + r) * 2048 + n0 + c]);
  }
  __syncthreads();
#pragma unroll
  for (int i = 0; i < 16; i++) {
    int r = rb + i * 4;
    WT[(size_t)(n0 + r) * 2048 + k0 + c] = tile[c][r];
  }
}

// ---------------------------------------------------------------------------
// Fused: h = LN1(x); x2 = h + x; h2 = LN2(x2).
// One WAVE per row (32 elems/lane); pure shfl_xor reductions, no barriers.
// ---------------------------------------------------------------------------
__global__ __launch_bounds__(256) void ln_fused(
    const float* __restrict__ x,
    const float* __restrict__ s1, const float* __restrict__ b1,
    const float* __restrict__ s2, const float* __restrict__ b2,
    u16* __restrict__ h_bf, float* __restrict__ x2o, u16* __restrict__ h2_bf) {
  const int wid = threadIdx.x >> 6, lane = threadIdx.x & 63;
  const size_t rbase = (size_t)(blockIdx.x * 4 + wid) * 2048;

  float v[32];
#pragma unroll
  for (int i = 0; i < 8; i++)
    *(float4*)&v[i * 4] = *(const float4*)(x + rbase + i * 256 + lane * 4);

  float s = 0.f;
#pragma unroll
  for (int i = 0; i < 32; i++) s += v[i];
#pragma unroll
  for (int off = 32; off; off >>= 1) s += __shfl_xor(s, off, 64);
  const float m1 = s * (1.f / 2048.f);

  float ss = 0.f;
#pragma unroll
  for (int i = 0; i < 32; i++) { float d = v[i] - m1; ss += d * d; }
#pragma unroll
  for (int off = 32; off; off >>= 1) ss += __shfl_xor(ss, off, 64);
  const float r1 = rsqrtf(ss * (1.f / 2048.f) + 1e-5f);

  float xx[32];
#pragma unroll
  for (int i = 0; i < 8; i++) {
    const int c = i * 256 + lane * 4;
    float4 w4 = *(const float4*)(s1 + c);
    float4 b4 = *(const float4*)(b1 + c);
    u16x4 hv;
#pragma unroll
    for (int j = 0; j < 4; j++) {
      float hh = (v[i * 4 + j] - m1) * r1 * (&w4.x)[j] + (&b4.x)[j];
      xx[i * 4 + j] = hh + v[i * 4 + j];
      hv[j] = f2bf(hh);
    }
    *(u16x4*)(h_bf + rbase + c) = hv;
    *(float4*)(x2o + rbase + c) = *(float4*)&xx[i * 4];
  }

  // LN2 on xx
  s = 0.f;
#pragma unroll
  for (int i = 0; i < 32; i++) s += xx[i];
#pragma unroll
  for (int off = 32; off; off >>= 1) s += __shfl_xor(s, off, 64);
  const float m2 = s * (1.f / 2048.f);

  ss = 0.f;
#pragma unroll
  for (int i = 0; i < 32; i++) { float d = xx[i] - m2; ss += d * d; }
#pragma unroll
  for (int off = 32; off; off >>= 1) ss += __shfl_xor(ss, off, 64);
  const float r2 = rsqrtf(ss * (1.f / 2048.f) + 1e-5f);

#pragma unroll
  for (int i = 0; i < 8; i++) {
    const int c = i * 256 + lane * 4;
    float4 w4 = *(const float4*)(s2 + c);
    float4 b4 = *(const float4*)(b2 + c);
    u16x4 hv;
#pragma unroll
    for (int j = 0; j < 4; j++)
      hv[j] = f2bf((xx[i * 4 + j] - m2) * r2 * (&w4.x)[j] + (&b4.x)[j]);
    *(u16x4*)(h2_bf + rbase + c) = hv;
  }
}

// ---------------------------------------------------------------------------
// bf16 MFMA GEMM (m97 structure): C[M=4096][N] = A[4096][2048] @ BT[N][2048]^T
// 128x128 block tile, BK=64, global_load_lds dwordx4 staging,
// 4 waves x (4x4) 16x16x32 MFMA tiles, 2-barrier K-loop.
// ---------------------------------------------------------------------------
template <int N, int BIAS, int RELU, int RESID, int OUTBF>
__global__ __launch_bounds__(256) void gemm_bf16(
    const u16* __restrict__ A, const u16* __restrict__ BT,
    const float* __restrict__ bias, const float* __restrict__ resid,
    void* __restrict__ Cout) {
  constexpr int K = 2048, BK = 64;
  __shared__ u16 As[128 * BK];   // 16 KB
  __shared__ u16 Bs[128 * BK];   // 16 KB
  const int tid = threadIdx.x;
  const int row0 = blockIdx.y * 128, col0 = blockIdx.x * 128;
  const int wid = tid >> 6, lane = tid & 63, lr = lane & 15, quad = lane >> 4;
  const int wr0 = (wid >> 1) * 64, wc0 = (wid & 1) * 64;
  const int srow = lane >> 3;           // 0..7 row within 8-row group
  const int scol = (lane & 7) * 8;      // u16 col within BK

  f32x4 acc[4][4];
#pragma unroll
  for (int i = 0; i < 4; i++)
#pragma unroll
    for (int j = 0; j < 4; j++) acc[i][j] = (f32x4){0.f, 0.f, 0.f, 0.f};

  const u16* gA = A + (size_t)(row0 + srow) * K + scol;
  const u16* gB = BT + (size_t)(col0 + srow) * K + scol;

  for (int k0 = 0; k0 < K; k0 += BK) {
    if (k0) __syncthreads();   // previous compute done before LDS overwrite
#pragma unroll
    for (int i = 0; i < 4; i++) {
      const int rg = i * 32 + wid * 8;              // wave-uniform row group
      gload_lds16(gA + (size_t)rg * K + k0, &As[rg * BK]);
      gload_lds16(gB + (size_t)rg * K + k0, &Bs[rg * BK]);
    }
    __syncthreads();           // compiler drains vmcnt(0) before s_barrier

#pragma unroll
    for (int kk = 0; kk < 2; kk++) {
      bf16x8 af[4], bfr[4];
#pragma unroll
      for (int i = 0; i < 4; i++)
        af[i] = *(const bf16x8*)&As[(wr0 + i * 16 + lr) * BK + kk * 32 + quad * 8];
#pragma unroll
      for (int j = 0; j < 4; j++)
        bfr[j] = *(const bf16x8*)&Bs[(wc0 + j * 16 + lr) * BK + kk * 32 + quad * 8];
#pragma unroll
      for (int i = 0; i < 4; i++)
#pragma unroll
        for (int j = 0; j < 4; j++) acc[i][j] = MFMA16(af[i], bfr[j], acc[i][j]);
    }
  }

  // epilogue: C row = quad*4 + reg, col = lane&15 (verified gfx950 C/D layout)
#pragma unroll
  for (int i = 0; i < 4; i++) {
#pragma unroll
    for (int r = 0; r < 4; r++) {
      const int row = row0 + wr0 + i * 16 + quad * 4 + r;
#pragma unroll
      for (int j = 0; j < 4; j++) {
        const int col = col0 + wc0 + j * 16 + lr;
        float v = acc[i][j][r];
        if (BIAS) v += bias[col];
        if (RELU) v = fmaxf(v, 0.f);
        if (RESID) v += resid[(size_t)row * N + col];
        if (OUTBF)
          ((u16*)Cout)[(size_t)row * N + col] = f2bf(v);
        else
          ((float*)Cout)[(size_t)row * N + col] = v;
      }
    }
  }
}

// ---------------------------------------------------------------------------
// Attention scores + softmax, fused. One block = (b, h, 16 q-rows).
// scores[16][1024] in LDS (64 KB), probs written exactly once to d_out.
// qk layout: [B*S][4096], q at col h*64, k at col 2048 + h*64 (merged GEMM).
// ---------------------------------------------------------------------------
__global__ __launch_bounds__(256) void attn_kernel(const u16* __restrict__ qk,
                                                   float* __restrict__ probs) {
  __shared__ float sc[16 * 1024];
  const int tid = threadIdx.x, wid = tid >> 6, lane = tid & 63;
  const int lr = lane & 15, quad = lane >> 4;
  const int q0 = blockIdx.x * 16, h = blockIdx.y, b = blockIdx.z;

  const size_t qbase = (size_t)(b * 1024 + q0 + lr) * 4096 + h * 64 + quad * 8;
  const bf16x8 a0 = *(const bf16x8*)(qk + qbase);
  const bf16x8 a1 = *(const bf16x8*)(qk + qbase + 32);
  const float scale = 0.022097086912079608f;  // 1/sqrt(2048)

  for (int t = 0; t < 16; t++) {
    const int c0 = wid * 256 + t * 16;
    const size_t kbase = (size_t)(b * 1024 + c0 + lr) * 4096 + 2048 + h * 64 + quad * 8;
    const bf16x8 b0 = *(const bf16x8*)(qk + kbase);
    const bf16x8 b1 = *(const bf16x8*)(qk + kbase + 32);
    f32x4 acc = (f32x4){0.f, 0.f, 0.f, 0.f};
    acc = MFMA16(a0, b0, acc);
    acc = MFMA16(a1, b1, acc);
#pragma unroll
    for (int r = 0; r < 4; r++) sc[(quad * 4 + r) * 1024 + c0 + lr] = acc[r] * scale;
  }
  __syncthreads();

  // softmax, float4-vectorized: lane handles cols {i*256 + lane*4 + 0..3}
#pragma unroll
  for (int rr = 0; rr < 4; rr++) {
    const int row = wid * 4 + rr;
    float vals[16];
#pragma unroll
    for (int i = 0; i < 4; i++)
      *(float4*)&vals[i * 4] = *(const float4*)&sc[row * 1024 + i * 256 + lane * 4];
    float mx = -1e30f;
#pragma unroll
    for (int i = 0; i < 16; i++) mx = fmaxf(mx, vals[i]);
#pragma unroll
    for (int off = 32; off; off >>= 1) mx = fmaxf(mx, __shfl_xor(mx, off, 64));
    float sum = 0.f;
#pragma unroll
    for (int i = 0; i < 16; i++) {
      vals[i] = __expf(vals[i] - mx);
      sum += vals[i];
    }
#pragma unroll
    for (int off = 32; off; off >>= 1) sum += __shfl_xor(sum, off, 64);
    const float inv = 1.f / sum;
    float* pr = probs + (size_t)((b * 32 + h) * 1024 + q0 + row) * 1024;
#pragma unroll
    for (int i = 0; i < 4; i++) {
      float4 o;
#pragma unroll
      for (int j = 0; j < 4; j++) (&o.x)[j] = vals[i * 4 + j] * inv;
      *(float4*)&pr[i * 256 + lane * 4] = o;
    }
  }
}

// ---------------------------------------------------------------------------
extern "C" void kernel_launch(void* const* d_in, const int* in_sizes, int n_in,
                              void* d_out, int out_size, void* d_ws, size_t ws_size,
                              hipStream_t stream) {
  const float* x = (const float*)d_in[0];
  const float* Wq = (const float*)d_in[1];
  const float* Wk = (const float*)d_in[2];
  // d_in[3] = Wv: dead in the reference (attended values are discarded)
  const float* ln1s = (const float*)d_in[4];
  const float* ln1b = (const float*)d_in[5];
  const float* ln2s = (const float*)d_in[6];
  const float* ln2b = (const float*)d_in[7];
  const float* f1w = (const float*)d_in[8];
  const float* f1b = (const float*)d_in[9];
  const float* f2w = (const float*)d_in[10];
  const float* f2b = (const float*)d_in[11];

  char* p = (char*)d_ws;
  const size_t WSZ = (size_t)2048 * 2048 * 2;   // 8 MB bf16 weight
  const size_t ASZ = (size_t)4096 * 2048 * 2;   // 16 MB bf16 activation
  u16* WqkT = (u16*)p; p += 2 * WSZ;            // [WqT; WkT] contiguous, 4096 rows
  u16* F1T = (u16*)p; p += WSZ;
  u16* F2T = (u16*)p; p += WSZ;
  u16* h_bf = (u16*)p; p += ASZ;
  u16* h2_bf = (u16*)p; p += ASZ;
  u16* qk_bf = (u16*)p; p += 2 * ASZ;           // [4096][4096] merged Q|K
  u16* a1_bf = (u16*)p; p += ASZ;
  float* x2 = (float*)p; p += (size_t)4096 * 2048 * 4;

  float* out = (float*)d_out;
  float* probs = out + (size_t)4096 * 2048;

  // all 4 weight transposes in one launch; dst order: WqT, WkT, F1T, F2T
  transpose_cast4<<<dim3(32, 32, 4), 256, 0, stream>>>(Wq, Wk, f1w, f2w, WqkT);

  ln_fused<<<1024, 256, 0, stream>>>(x, ln1s, ln1b, ln2s, ln2b, h_bf, x2, h2_bf);

  // merged Q|K projection: C[4096][4096] = h @ [Wq|Wk]
  gemm_bf16<4096, 0, 0, 0, 1><<<dim3(32, 32), 256, 0, stream>>>(
      h_bf, WqkT, nullptr, nullptr, qk_bf);

  attn_kernel<<<dim3(64, 32, 4), 256, 0, stream>>>(qk_bf, probs);

  const dim3 gg(16, 32);
  gemm_bf16<2048, 1, 1, 0, 1><<<gg, 256, 0, stream>>>(h2_bf, F1T, f1b, nullptr, a1_bf);
  gemm_bf16<2048, 1, 0, 1, 0><<<gg, 256, 0, stream>>>(a1_bf, F2T, f2b, x2, out);
}

// Round 3
// 893.000 us; speedup vs baseline: 1.1651x; 1.1035x over previous
//
#include <hip/hip_runtime.h>
#include <math.h>

// TransformerLayer fused implementation for MI355X (gfx950).
// Reference quirks kept faithful:
//  - v / attended_values are DEAD code in the reference -> Wv never touched.
//  - scores scaled by 1/sqrt(D)=1/sqrt(2048), not 1/sqrt(head_dim).
//  - x2 = LN1(x) + x  (residual added to LN output).
// Outputs (concat in d_out): out [4,1024,2048] fp32, attn_probs [4,32,1024,1024] fp32.
//
// R3 changes:
//  - attn: sc LDS writes XOR-swizzled (4-way -> 2-way bank conflict, 2-way is free),
//    probs written with non-temporal stores (512 MB write-once, keep L2/LLC clean).
//  - transpose_cast4 + ln_fused merged into one prep launch (branch on blockIdx).

typedef unsigned short u16;
typedef u16    u16x4  __attribute__((ext_vector_type(4)));
typedef u16    u16x8  __attribute__((ext_vector_type(8)));
typedef __bf16 bf16x8 __attribute__((ext_vector_type(8)));
typedef float  f32x4  __attribute__((ext_vector_type(4)));

#define MFMA16(a, b, c) __builtin_amdgcn_mfma_f32_16x16x32_bf16((a), (b), (c), 0, 0, 0)

__device__ __forceinline__ u16 f2bf(float f) {
  unsigned u = __builtin_bit_cast(unsigned, f);
  u += 0x7fffu + ((u >> 16) & 1u);   // RNE
  return (u16)(u >> 16);
}

// global -> LDS direct copy, 16 B per lane. LDS dest must be wave-uniform;
// HW writes ldsbase + lane*16.
__device__ __forceinline__ void gload_lds16(const u16* g, u16* l) {
  __builtin_amdgcn_global_load_lds(
      (const __attribute__((address_space(1))) unsigned int*)g,
      (__attribute__((address_space(3))) unsigned int*)l, 16, 0, 0);
}

__device__ __forceinline__ void nt_store4(float* p, f32x4 v) {
  __builtin_nontemporal_store(v, (f32x4*)p);
}

// ---------------------------------------------------------------------------
// Prep kernel: blocks [0,4096) transpose+cast the 4 weights; blocks
// [4096,5120) run the fused LN pipeline (independent work, one launch).
// ---------------------------------------------------------------------------
__global__ __launch_bounds__(256) void prep_kernel(
    const float* __restrict__ W0, const float* __restrict__ W1,
    const float* __restrict__ W2, const float* __restrict__ W3,
    u16* __restrict__ dst,
    const float* __restrict__ x,
    const float* __restrict__ s1, const float* __restrict__ b1,
    const float* __restrict__ s2, const float* __restrict__ b2,
    u16* __restrict__ h_bf, float* __restrict__ x2o, u16* __restrict__ h2_bf) {
  __shared__ u16 tile[64][65];
  const int bx = blockIdx.x;
  if (bx < 4096) {
    // ---- weight transpose + fp32->bf16 cast: W[K][N] -> WT[N][K] ----
    const int z = bx >> 10, rem = bx & 1023;
    const float* W = (z == 0) ? W0 : (z == 1) ? W1 : (z == 2) ? W2 : W3;
    u16* WT = dst + (size_t)z * 2048 * 2048;
    const int n0 = (rem & 31) * 64, k0 = (rem >> 5) * 64;
    const int c = threadIdx.x & 63, rb = threadIdx.x >> 6;
#pragma unroll
    for (int i = 0; i < 16; i++) {
      int r = rb + i * 4;
      tile[r][c] = f2bf(W[(size_t)(k0 + r) * 2048 + n0 + c]);
    }
    __syncthreads();
#pragma unroll
    for (int i = 0; i < 16; i++) {
      int r = rb + i * 4;
      WT[(size_t)(n0 + r) * 2048 + k0 + c] = tile[c][r];
    }
    return;
  }

  // ---- h = LN1(x); x2 = h + x; h2 = LN2(x2). One wave per row. ----
  const int wid = threadIdx.x >> 6, lane = threadIdx.x & 63;
  const size_t rbase = (size_t)((bx - 4096) * 4 + wid) * 2048;

  float v[32];
#pragma unroll
  for (int i = 0; i < 8; i++)
    *(float4*)&v[i * 4] = *(const float4*)(x + rbase + i * 256 + lane * 4);

  float s = 0.f;
#pragma unroll
  for (int i = 0; i < 32; i++) s += v[i];
#pragma unroll
  for (int off = 32; off; off >>= 1) s += __shfl_xor(s, off, 64);
  const float m1 = s * (1.f / 2048.f);

  float ss = 0.f;
#pragma unroll
  for (int i = 0; i < 32; i++) { float d = v[i] - m1; ss += d * d; }
#pragma unroll
  for (int off = 32; off; off >>= 1) ss += __shfl_xor(ss, off, 64);
  const float r1 = rsqrtf(ss * (1.f / 2048.f) + 1e-5f);

  float xx[32];
#pragma unroll
  for (int i = 0; i < 8; i++) {
    const int c = i * 256 + lane * 4;
    float4 w4 = *(const float4*)(s1 + c);
    float4 b4 = *(const float4*)(b1 + c);
    u16x4 hv;
#pragma unroll
    for (int j = 0; j < 4; j++) {
      float hh = (v[i * 4 + j] - m1) * r1 * (&w4.x)[j] + (&b4.x)[j];
      xx[i * 4 + j] = hh + v[i * 4 + j];
      hv[j] = f2bf(hh);
    }
    *(u16x4*)(h_bf + rbase + c) = hv;
    *(float4*)(x2o + rbase + c) = *(float4*)&xx[i * 4];
  }

  s = 0.f;
#pragma unroll
  for (int i = 0; i < 32; i++) s += xx[i];
#pragma unroll
  for (int off = 32; off; off >>= 1) s += __shfl_xor(s, off, 64);
  const float m2 = s * (1.f / 2048.f);

  ss = 0.f;
#pragma unroll
  for (int i = 0; i < 32; i++) { float d = xx[i] - m2; ss += d * d; }
#pragma unroll
  for (int off = 32; off; off >>= 1) ss += __shfl_xor(ss, off, 64);
  const float r2 = rsqrtf(ss * (1.f / 2048.f) + 1e-5f);

#pragma unroll
  for (int i = 0; i < 8; i++) {
    const int c = i * 256 + lane * 4;
    float4 w4 = *(const float4*)(s2 + c);
    float4 b4 = *(const float4*)(b2 + c);
    u16x4 hv;
#pragma unroll
    for (int j = 0; j < 4; j++)
      hv[j] = f2bf((xx[i * 4 + j] - m2) * r2 * (&w4.x)[j] + (&b4.x)[j]);
    *(u16x4*)(h2_bf + rbase + c) = hv;
  }
}

// ---------------------------------------------------------------------------
// bf16 MFMA GEMM (m97 structure): C[M=4096][N] = A[4096][2048] @ BT[N][2048]^T
// 128x128 block tile, BK=64, global_load_lds dwordx4 staging,
// 4 waves x (4x4) 16x16x32 MFMA tiles, 2-barrier K-loop.
// ---------------------------------------------------------------------------
template <int N, int BIAS, int RELU, int RESID, int OUTBF>
__global__ __launch_bounds__(256) void gemm_bf16(
    const u16* __restrict__ A, const u16* __restrict__ BT,
    const float* __restrict__ bias, const float* __restrict__ resid,
    void* __restrict__ Cout) {
  constexpr int K = 2048, BK = 64;
  __shared__ u16 As[128 * BK];   // 16 KB
  __shared__ u16 Bs[128 * BK];   // 16 KB
  const int tid = threadIdx.x;
  const int row0 = blockIdx.y * 128, col0 = blockIdx.x * 128;
  const int wid = tid >> 6, lane = tid & 63, lr = lane & 15, quad = lane >> 4;
  const int wr0 = (wid >> 1) * 64, wc0 = (wid & 1) * 64;
  const int srow = lane >> 3;           // 0..7 row within 8-row group
  const int scol = (lane & 7) * 8;      // u16 col within BK

  f32x4 acc[4][4];
#pragma unroll
  for (int i = 0; i < 4; i++)
#pragma unroll
    for (int j = 0; j < 4; j++) acc[i][j] = (f32x4){0.f, 0.f, 0.f, 0.f};

  const u16* gA = A + (size_t)(row0 + srow) * K + scol;
  const u16* gB = BT + (size_t)(col0 + srow) * K + scol;

  for (int k0 = 0; k0 < K; k0 += BK) {
    if (k0) __syncthreads();   // previous compute done before LDS overwrite
#pragma unroll
    for (int i = 0; i < 4; i++) {
      const int rg = i * 32 + wid * 8;              // wave-uniform row group
      gload_lds16(gA + (size_t)rg * K + k0, &As[rg * BK]);
      gload_lds16(gB + (size_t)rg * K + k0, &Bs[rg * BK]);
    }
    __syncthreads();           // compiler drains vmcnt(0) before s_barrier

#pragma unroll
    for (int kk = 0; kk < 2; kk++) {
      bf16x8 af[4], bfr[4];
#pragma unroll
      for (int i = 0; i < 4; i++)
        af[i] = *(const bf16x8*)&As[(wr0 + i * 16 + lr) * BK + kk * 32 + quad * 8];
#pragma unroll
      for (int j = 0; j < 4; j++)
        bfr[j] = *(const bf16x8*)&Bs[(wc0 + j * 16 + lr) * BK + kk * 32 + quad * 8];
#pragma unroll
      for (int i = 0; i < 4; i++)
#pragma unroll
        for (int j = 0; j < 4; j++) acc[i][j] = MFMA16(af[i], bfr[j], acc[i][j]);
    }
  }

  // epilogue: C row = quad*4 + reg, col = lane&15 (verified gfx950 C/D layout)
#pragma unroll
  for (int i = 0; i < 4; i++) {
#pragma unroll
    for (int r = 0; r < 4; r++) {
      const int row = row0 + wr0 + i * 16 + quad * 4 + r;
#pragma unroll
      for (int j = 0; j < 4; j++) {
        const int col = col0 + wc0 + j * 16 + lr;
        float v = acc[i][j][r];
        if (BIAS) v += bias[col];
        if (RELU) v = fmaxf(v, 0.f);
        if (RESID) v += resid[(size_t)row * N + col];
        if (OUTBF)
          ((u16*)Cout)[(size_t)row * N + col] = f2bf(v);
        else
          ((float*)Cout)[(size_t)row * N + col] = v;
      }
    }
  }
}

// ---------------------------------------------------------------------------
// Attention scores + softmax, fused. One block = (b, h, 16 q-rows).
// scores[16][1024] in LDS (64 KB), XOR-swizzled at 16-float-chunk granularity:
// logical chunk c16 of row r lives at physical chunk c16 ^ ((r>>2)&1).
// Store side: rows = quad*4+r -> s = quad&1 (spreads the 4 quads into 2 bank
// groups: 4-way conflict -> 2-way, which is free). Read side applies the same
// involution, so logical values are unchanged.
// probs written exactly once -> non-temporal stores (don't pollute L2/LLC).
// qk layout: [B*S][4096], q at col h*64, k at col 2048 + h*64 (merged GEMM).
// ---------------------------------------------------------------------------
__global__ __launch_bounds__(256) void attn_kernel(const u16* __restrict__ qk,
                                                   float* __restrict__ probs) {
  __shared__ float sc[16 * 1024];
  const int tid = threadIdx.x, wid = tid >> 6, lane = tid & 63;
  const int lr = lane & 15, quad = lane >> 4;
  const int q0 = blockIdx.x * 16, h = blockIdx.y, b = blockIdx.z;

  const size_t qbase = (size_t)(b * 1024 + q0 + lr) * 4096 + h * 64 + quad * 8;
  const bf16x8 a0 = *(const bf16x8*)(qk + qbase);
  const bf16x8 a1 = *(const bf16x8*)(qk + qbase + 32);
  const float scale = 0.022097086912079608f;  // 1/sqrt(2048)

  const int ssw = quad & 1;  // store-side swizzle bit ((row>>2)&1, row=quad*4+r)
  for (int t = 0; t < 16; t++) {
    const int c0 = wid * 256 + t * 16;
    const size_t kbase = (size_t)(b * 1024 + c0 + lr) * 4096 + 2048 + h * 64 + quad * 8;
    const bf16x8 b0 = *(const bf16x8*)(qk + kbase);
    const bf16x8 b1 = *(const bf16x8*)(qk + kbase + 32);
    f32x4 acc = (f32x4){0.f, 0.f, 0.f, 0.f};
    acc = MFMA16(a0, b0, acc);
    acc = MFMA16(a1, b1, acc);
    const int pc = ((wid * 16 + t) ^ ssw) * 16 + lr;  // physical col
#pragma unroll
    for (int r = 0; r < 4; r++) sc[(quad * 4 + r) * 1024 + pc] = acc[r] * scale;
  }
  __syncthreads();

  // softmax, float4-vectorized; lane handles logical cols {i*256 + lane*4 + 0..3}
  const int rsw = wid & 1;  // read-side swizzle bit ((row>>2)&1, row=wid*4+rr)
#pragma unroll
  for (int rr = 0; rr < 4; rr++) {
    const int row = wid * 4 + rr;
    float vals[16];
#pragma unroll
    for (int i = 0; i < 4; i++) {
      const int pidx = (i * 16 + ((lane >> 2) ^ rsw)) * 16 + (lane & 3) * 4;
      *(f32x4*)&vals[i * 4] = *(const f32x4*)&sc[row * 1024 + pidx];
    }
    float mx = -1e30f;
#pragma unroll
    for (int i = 0; i < 16; i++) mx = fmaxf(mx, vals[i]);
#pragma unroll
    for (int off = 32; off; off >>= 1) mx = fmaxf(mx, __shfl_xor(mx, off, 64));
    float sum = 0.f;
#pragma unroll
    for (int i = 0; i < 16; i++) {
      vals[i] = __expf(vals[i] - mx);
      sum += vals[i];
    }
#pragma unroll
    for (int off = 32; off; off >>= 1) sum += __shfl_xor(sum, off, 64);
    const float inv = 1.f / sum;
    float* pr = probs + (size_t)((b * 32 + h) * 1024 + q0 + row) * 1024;
#pragma unroll
    for (int i = 0; i < 4; i++) {
      f32x4 o;
#pragma unroll
      for (int j = 0; j < 4; j++) o[j] = vals[i * 4 + j] * inv;
      nt_store4(&pr[i * 256 + lane * 4], o);
    }
  }
}

// ---------------------------------------------------------------------------
extern "C" void kernel_launch(void* const* d_in, const int* in_sizes, int n_in,
                              void* d_out, int out_size, void* d_ws, size_t ws_size,
                              hipStream_t stream) {
  const float* x = (const float*)d_in[0];
  const float* Wq = (const float*)d_in[1];
  const float* Wk = (const float*)d_in[2];
  // d_in[3] = Wv: dead in the reference (attended values are discarded)
  const float* ln1s = (const float*)d_in[4];
  const float* ln1b = (const float*)d_in[5];
  const float* ln2s = (const float*)d_in[6];
  const float* ln2b = (const float*)d_in[7];
  const float* f1w = (const float*)d_in[8];
  const float* f1b = (const float*)d_in[9];
  const float* f2w = (const float*)d_in[10];
  const float* f2b = (const float*)d_in[11];

  char* p = (char*)d_ws;
  const size_t WSZ = (size_t)2048 * 2048 * 2;   // 8 MB bf16 weight
  const size_t ASZ = (size_t)4096 * 2048 * 2;   // 16 MB bf16 activation
  u16* WqkT = (u16*)p; p += 2 * WSZ;            // [WqT; WkT] contiguous, 4096 rows
  u16* F1T = (u16*)p; p += WSZ;
  u16* F2T = (u16*)p; p += WSZ;
  u16* h_bf = (u16*)p; p += ASZ;
  u16* h2_bf = (u16*)p; p += ASZ;
  u16* qk_bf = (u16*)p; p += 2 * ASZ;           // [4096][4096] merged Q|K
  u16* a1_bf = (u16*)p; p += ASZ;
  float* x2 = (float*)p; p += (size_t)4096 * 2048 * 4;

  float* out = (float*)d_out;
  float* probs = out + (size_t)4096 * 2048;

  // transposes (blocks 0..4095) + LN pipeline (blocks 4096..5119), one launch
  prep_kernel<<<5120, 256, 0, stream>>>(Wq, Wk, f1w, f2w, WqkT,
                                        x, ln1s, ln1b, ln2s, ln2b,
                                        h_bf, x2, h2_bf);

  // merged Q|K projection: C[4096][4096] = h @ [Wq|Wk]
  gemm_bf16<4096, 0, 0, 0, 1><<<dim3(32, 32), 256, 0, stream>>>(
      h_bf, WqkT, nullptr, nullptr, qk_bf);

  attn_kernel<<<dim3(64, 32, 4), 256, 0, stream>>>(qk_bf, probs);

  const dim3 gg(16, 32);
  gemm_bf16<2048, 1, 1, 0, 1><<<gg, 256, 0, stream>>>(h2_bf, F1T, f1b, nullptr, a1_bf);
  gemm_bf16<2048, 1, 0, 1, 0><<<gg, 256, 0, stream>>>(a1_bf, F2T, f2b, x2, out);
}